// Round 5
// baseline (271.758 us; speedup 1.0000x reference)
//
#include <hip/hip_runtime.h>
#include <math.h>

#define KNN 20
#define NPTS 4096
#define BATCH 8
#define P_TOT (BATCH * NPTS)       // 32768
#define QPW 8                      // queries per wave
#define WPB 8                      // waves per block (512 threads)
#define QPB (QPW * WPB)            // 64 queries per block
#define NBLK (P_TOT / QPB)         // 512 blocks
#define BPB (NPTS / QPB)           // 64 blocks per batch
#define BN_EPS 1e-5
#define NEG_SLOPE 0.2f

// float-offsets into ws
#define FO_CLOUD 0                 // 32768 float4 = 131072 floats
#define FO_PART  131072            // 512 x 128 block partials
#define FO_PART2 196608            // 64 x 128 stage-2 partials
#define FO_AB    655360            // 128 floats (a, shift)
#define FO_W2    655488            // 448 floats (folded W + bias)
#define FO_BIG   655936            // rawmin (2097152 f) or idx (655360 i)

// ---------- kernel 1: pack cloud as float4 (x,y,z,|p|^2) ----------
__global__ __launch_bounds__(256) void pack_kernel(const float* __restrict__ pcd,
                                                   float4* __restrict__ cloud) {
    int i = blockIdx.x * 256 + threadIdx.x;
    float x = pcd[3 * i], y = pcd[3 * i + 1], z = pcd[3 * i + 2];
    float sq = __fadd_rn(__fadd_rn(__fmul_rn(x, x), __fmul_rn(y, y)), __fmul_rn(z, z));
    cloud[i] = make_float4(x, y, z, sq);
}

// distance, bit-exact vs reference (validated R1-R4)
__device__ __forceinline__ float distf(float4 C, float qx, float qy, float qz, float qs) {
    float dot_ = __fadd_rn(__fadd_rn(__fmul_rn(qx, C.x), __fmul_rn(qy, C.y)),
                           __fmul_rn(qz, C.z));
    return fmaf(-2.0f, dot_, __fadd_rn(qs, C.w));
}

// top-2 maintenance (strict <, first-seen kept -> lowest slot on ties)
__device__ __forceinline__ void upd2(float& v1, float& v2, int& s1, int& s2, float dd, int j) {
    const bool c1 = dd < v1;
    const bool c2 = dd < v2;
    v2 = c1 ? v1 : (c2 ? dd : v2);
    s2 = c1 ? s1 : (c2 ? j : s2);
    v1 = c1 ? dd : v1;
    s1 = c1 ? j : s1;
}

// wave-wide min via explicit swizzles: 5 xor steps within 32-lane halves + cross-half bpermute
__device__ __forceinline__ float wmin_f(float v, int a32) {
    v = fminf(v, __int_as_float(__builtin_amdgcn_ds_swizzle(__float_as_int(v), 0x041F)));
    v = fminf(v, __int_as_float(__builtin_amdgcn_ds_swizzle(__float_as_int(v), 0x081F)));
    v = fminf(v, __int_as_float(__builtin_amdgcn_ds_swizzle(__float_as_int(v), 0x101F)));
    v = fminf(v, __int_as_float(__builtin_amdgcn_ds_swizzle(__float_as_int(v), 0x201F)));
    v = fminf(v, __int_as_float(__builtin_amdgcn_ds_swizzle(__float_as_int(v), 0x401F)));
    v = fminf(v, __int_as_float(__builtin_amdgcn_ds_bpermute(a32, __float_as_int(v))));
    return v;
}
__device__ __forceinline__ int wmin_i(int v, int a32) {
    v = min(v, __builtin_amdgcn_ds_swizzle(v, 0x041F));
    v = min(v, __builtin_amdgcn_ds_swizzle(v, 0x081F));
    v = min(v, __builtin_amdgcn_ds_swizzle(v, 0x101F));
    v = min(v, __builtin_amdgcn_ds_swizzle(v, 0x201F));
    v = min(v, __builtin_amdgcn_ds_swizzle(v, 0x401F));
    v = min(v, __builtin_amdgcn_ds_bpermute(a32, v));
    return v;
}

// promote group G's second to first, or recompute top-2 from LDS (static G)
template <int G>
__device__ __forceinline__ void prom(float (&gv1)[8], float (&gv2)[8], int (&gs1)[8], int (&gs2)[8],
                                     unsigned long long mask, const float4* cl, int lane,
                                     float qx, float qy, float qz, float qs) {
    if (gv2[G] < INFINITY) {
        gv1[G] = gv2[G]; gs1[G] = gs2[G]; gv2[G] = INFINITY;
    } else {
        float m1 = INFINITY, m2 = INFINITY; int s1 = 0, s2 = 0;
#pragma unroll
        for (int e = 0; e < 8; ++e) {
            const int sl = G * 8 + e;
            const float4 C = cl[sl * 64 + lane];
            float dd = distf(C, qx, qy, qz, qs);
            if ((mask >> sl) & 1ull) dd = INFINITY;
            upd2(m1, m2, s1, s2, dd, sl);
        }
        gv1[G] = m1; gv2[G] = m2; gs1[G] = s1; gs2[G] = s2;
    }
}

__device__ __forceinline__ void repair(float (&gv1)[8], float (&gv2)[8], int (&gs1)[8], int (&gs2)[8],
                                       unsigned long long& mask, float& dmin, int& mmin,
                                       int win, int lane, const float4* cl,
                                       float qx, float qy, float qz, float qs) {
    const int slot = win >> 6;
    mask |= (1ull << slot);
    switch (slot >> 3) {
        case 0: prom<0>(gv1, gv2, gs1, gs2, mask, cl, lane, qx, qy, qz, qs); break;
        case 1: prom<1>(gv1, gv2, gs1, gs2, mask, cl, lane, qx, qy, qz, qs); break;
        case 2: prom<2>(gv1, gv2, gs1, gs2, mask, cl, lane, qx, qy, qz, qs); break;
        case 3: prom<3>(gv1, gv2, gs1, gs2, mask, cl, lane, qx, qy, qz, qs); break;
        case 4: prom<4>(gv1, gv2, gs1, gs2, mask, cl, lane, qx, qy, qz, qs); break;
        case 5: prom<5>(gv1, gv2, gs1, gs2, mask, cl, lane, qx, qy, qz, qs); break;
        case 6: prom<6>(gv1, gv2, gs1, gs2, mask, cl, lane, qx, qy, qz, qs); break;
        default: prom<7>(gv1, gv2, gs1, gs2, mask, cl, lane, qx, qy, qz, qs); break;
    }
    float nv = gv1[0]; int ns = gs1[0];
#pragma unroll
    for (int g = 1; g < 8; ++g) if (gv1[g] < nv) { nv = gv1[g]; ns = gs1[g]; }
    dmin = nv; mmin = ns * 64 + lane;
}

// ---------- kernel 2: fused kNN (2 queries interleaved) + stats + raw max/min ----------
template <bool FAST>
__global__ __launch_bounds__(512, 2) void knn_kernel(const float4* __restrict__ cloud,
                                                     const float* __restrict__ W,
                                                     const float* __restrict__ bias,
                                                     float* __restrict__ partials,
                                                     float* __restrict__ rawmax,
                                                     float* __restrict__ rawmin,
                                                     int* __restrict__ idxo) {
    __shared__ float4 cl[NPTS];    // 64 KB
    const int t = threadIdx.x;
    const int wave = t >> 6, lane = t & 63;
    const int a32 = ((lane ^ 32) << 2);
    const int bidx = blockIdx.x;
    const int batch = bidx / BPB;
    const int gbase = batch * NPTS;

#pragma unroll
    for (int it = 0; it < NPTS / 512; ++it)
        cl[it * 512 + t] = cloud[gbase + it * 512 + t];
    __syncthreads();

    // folded MLP: raw = qoff + wd0*Cx + wd1*Cy + wd2*Cz
    const float wc3 = W[192 + lane], wc4 = W[256 + lane], wc5 = W[320 + lane];
    const float wd0 = W[lane] - wc3, wd1 = W[64 + lane] - wc4, wd2 = W[128 + lane] - wc5;
    const float bb = bias[lane];
    float se = 0.f, sqs = 0.f;

#pragma unroll 1
    for (int qi = 0; qi < QPW / 2; ++qi) {
        const int qA = (bidx % BPB) * QPB + wave * QPW + qi * 2;   // in-batch query ids
        const int qB = qA + 1;
        const int gqA = gbase + qA, gqB = gbase + qB;
        const float4 QA = cl[qA];
        const float4 QB = cl[qB];
        const float qxA = QA.x, qyA = QA.y, qzA = QA.z, qsA = QA.w;
        const float qxB = QB.x, qyB = QB.y, qzB = QB.z, qsB = QB.w;
        const float qoffA = fmaf(wc3, qxA, fmaf(wc4, qyA, fmaf(wc5, qzA, bb)));
        const float qoffB = fmaf(wc3, qxB, fmaf(wc4, qyB, fmaf(wc5, qzB, bb)));

        // ---- distance pass: one LDS sweep serves both queries ----
        float gv1A[8], gv2A[8], gv1B[8], gv2B[8];
        int gs1A[8], gs2A[8], gs1B[8], gs2B[8];
#pragma unroll
        for (int g = 0; g < 8; ++g) {
            gv1A[g] = INFINITY; gv2A[g] = INFINITY; gs1A[g] = 0; gs2A[g] = 0;
            gv1B[g] = INFINITY; gv2B[g] = INFINITY; gs1B[g] = 0; gs2B[g] = 0;
        }
#pragma unroll
        for (int g = 0; g < 8; ++g) {
#pragma unroll
            for (int e = 0; e < 8; ++e) {
                const int j = g * 8 + e;
                const float4 C = cl[j * 64 + lane];
                const float ddA = distf(C, qxA, qyA, qzA, qsA);
                const float ddB = distf(C, qxB, qyB, qzB, qsB);
                upd2(gv1A[g], gv2A[g], gs1A[g], gs2A[g], ddA, j);
                upd2(gv1B[g], gv2B[g], gs1B[g], gs2B[g], ddB, j);
            }
            __builtin_amdgcn_sched_barrier(0);   // cap live loads at one group
        }
        float dminA = gv1A[0]; int bsA = gs1A[0];
        float dminB = gv1B[0]; int bsB = gs1B[0];
#pragma unroll
        for (int g = 1; g < 8; ++g) {
            if (gv1A[g] < dminA) { dminA = gv1A[g]; bsA = gs1A[g]; }
            if (gv1B[g] < dminB) { dminB = gv1B[g]; bsB = gs1B[g]; }
        }
        int mminA = bsA * 64 + lane;
        int mminB = bsB * 64 + lane;
        unsigned long long maskA = 0ull, maskB = 0ull;
        float hmaxA = -INFINITY, hminA = INFINITY;
        float hmaxB = -INFINITY, hminB = INFINITY;

#pragma unroll 1
        for (int p = 0; p < KNN; ++p) {
            const float gA = wmin_f(dminA, a32);
            const float gB = wmin_f(dminB, a32);
            const unsigned long long balA = __ballot(dminA == gA);
            const unsigned long long balB = __ballot(dminB == gB);
            int winA, winB;
            if (__builtin_expect(__popcll(balA) > 1, 0)) {
                winA = wmin_i((dminA == gA) ? mminA : 0x7FFFFFFF, a32);  // tie: lowest index
            } else {
                winA = __builtin_amdgcn_readlane(mminA, (int)(__ffsll(balA) - 1));
            }
            if (__builtin_expect(__popcll(balB) > 1, 0)) {
                winB = wmin_i((dminB == gB) ? mminB : 0x7FFFFFFF, a32);
            } else {
                winB = __builtin_amdgcn_readlane(mminB, (int)(__ffsll(balB) - 1));
            }

            if (!FAST) {
                if (lane == 0) {
                    idxo[gqA * KNN + p] = winA;
                    idxo[gqB * KNN + p] = winB;
                }
            }

            // ---- fused channel phase (lane = channel), uniform broadcast ----
            const float4 CA = cl[winA];
            const float4 CB = cl[winB];
            const float rawA = fmaf(wd0, CA.x, fmaf(wd1, CA.y, fmaf(wd2, CA.z, qoffA)));
            const float rawB = fmaf(wd0, CB.x, fmaf(wd1, CB.y, fmaf(wd2, CB.z, qoffB)));
            se += rawA; sqs = fmaf(rawA, rawA, sqs);
            hmaxA = fmaxf(hmaxA, rawA); hminA = fminf(hminA, rawA);
            se += rawB; sqs = fmaf(rawB, rawB, sqs);
            hmaxB = fmaxf(hmaxB, rawB); hminB = fminf(hminB, rawB);

            // ---- owner-lane repair ----
            if ((winA & 63) == lane)
                repair(gv1A, gv2A, gs1A, gs2A, maskA, dminA, mminA, winA, lane, cl, qxA, qyA, qzA, qsA);
            if ((winB & 63) == lane)
                repair(gv1B, gv2B, gs1B, gs2B, maskB, dminB, mminB, winB, lane, cl, qxB, qyB, qzB, qsB);
        }

        if (FAST) {
            rawmax[gqA * 64 + lane] = hmaxA;
            rawmin[gqA * 64 + lane] = hminA;
            rawmax[gqB * 64 + lane] = hmaxB;
            rawmin[gqB * 64 + lane] = hminB;
        }
    }

    // ---- cross-wave stats reduce (reuse cl LDS) ----
    __syncthreads();
    float* sred = (float*)cl;
    sred[wave * 128 + lane] = se;
    sred[wave * 128 + 64 + lane] = sqs;
    __syncthreads();
    if (t < 128) {
        float s = 0.f;
#pragma unroll
        for (int w = 0; w < WPB; ++w) s += sred[w * 128 + t];
        partials[bidx * 128 + t] = s;
    }
}

// ---------- kernel 3a: reduce 512 block-partials -> 64 ----------
__global__ __launch_bounds__(128) void finA_kernel(const float* __restrict__ partials,
                                                   float* __restrict__ part2) {
    const int b = blockIdx.x, t = threadIdx.x;   // 64 blocks x 128 threads
    float s = 0.f;
#pragma unroll
    for (int i = 0; i < 8; ++i) s += partials[(b * 8 + i) * 128 + t];
    part2[b * 128 + t] = s;
}

// ---------- kernel 3b: finalize BN, fold affine ----------
__global__ __launch_bounds__(64) void finB_kernel(const float* __restrict__ part2,
                                                  const float* __restrict__ W,
                                                  const float* __restrict__ bias,
                                                  const float* __restrict__ gamma,
                                                  const float* __restrict__ beta,
                                                  float* __restrict__ ab,
                                                  float* __restrict__ w2) {
    const int c = threadIdx.x;   // 64 threads
    double s0 = 0.0, s1 = 0.0, q0 = 0.0, q1 = 0.0;
    for (int i = 0; i < 64; i += 2) {
        s0 += (double)part2[i * 128 + c];
        q0 += (double)part2[i * 128 + 64 + c];
        s1 += (double)part2[(i + 1) * 128 + c];
        q1 += (double)part2[(i + 1) * 128 + 64 + c];
    }
    const double cnt = (double)P_TOT * KNN;
    double mean = (s0 + s1) / cnt;
    double var = (q0 + q1) / cnt - mean * mean;
    double a = (double)gamma[c] / sqrt(var + BN_EPS);
    float af = (float)a;
    float sh = (float)((double)beta[c] - mean * a);
    ab[c] = af;
    ab[64 + c] = sh;
#pragma unroll
    for (int f = 0; f < 6; ++f) w2[f * 64 + c] = W[f * 64 + c] * af;
    w2[384 + c] = fmaf(bias[c], af, sh);
}

// ---------- kernel 4a (fast): elementwise BN+LeakyReLU on raw max/min ----------
__global__ __launch_bounds__(256) void final_kernel(const float* __restrict__ ab,
                                                    const float* __restrict__ rawmin,
                                                    float* __restrict__ out) {
    int i = blockIdx.x * 256 + threadIdx.x;
    int c = i & 63;
    float a = ab[c], sh = ab[64 + c];
    float va = fmaf(a, out[i], sh);       // out currently holds rawmax
    float vb = fmaf(a, rawmin[i], sh);
    va = va >= 0.f ? va : NEG_SLOPE * va;
    vb = vb >= 0.f ? vb : NEG_SLOPE * vb;
    out[i] = fmaxf(va, vb);               // monotone: covers a>=0 and a<0
}

// ---------- kernel 4b (fallback): gather + folded MLP + maxpool ----------
__global__ __launch_bounds__(256) void out_kernel(const float4* __restrict__ cloud,
                                                  const int* __restrict__ idxo,
                                                  const float* __restrict__ w2,
                                                  float* __restrict__ out) {
    const int t = threadIdx.x, c = t & 63;
    const int gp = blockIdx.x * 4 + (t >> 6);
    const int gb = gp & ~(NPTS - 1);
    const float wc0 = w2[c], wc1 = w2[64 + c], wc2 = w2[128 + c];
    const float wc3 = w2[192 + c], wc4 = w2[256 + c], wc5 = w2[320 + c];
    const float bc = w2[384 + c];
    const float4 Q = cloud[gp];
    float vmax = -INFINITY;
    for (int k = 0; k < KNN; ++k) {
        const int m = idxo[gp * KNN + k];
        const float4 C = cloud[gb + m];
        float h = bc;
        h = fmaf(wc0, C.x, h);
        h = fmaf(wc1, C.y, h);
        h = fmaf(wc2, C.z, h);
        h = fmaf(wc3, Q.x - C.x, h);
        h = fmaf(wc4, Q.y - C.y, h);
        h = fmaf(wc5, Q.z - C.z, h);
        h = h >= 0.f ? h : NEG_SLOPE * h;
        vmax = fmaxf(vmax, h);
    }
    out[gp * 64 + c] = vmax;
}

extern "C" void kernel_launch(void* const* d_in, const int* in_sizes, int n_in,
                              void* d_out, int out_size, void* d_ws, size_t ws_size,
                              hipStream_t stream) {
    const float* pcd   = (const float*)d_in[0];
    const float* W     = (const float*)d_in[1];
    const float* bias  = (const float*)d_in[2];
    const float* gamma = (const float*)d_in[3];
    const float* beta  = (const float*)d_in[4];

    float* wsf = (float*)d_ws;
    float4* cloud   = (float4*)(wsf + FO_CLOUD);
    float* partials = wsf + FO_PART;
    float* part2    = wsf + FO_PART2;
    float* ab       = wsf + FO_AB;
    float* w2       = wsf + FO_W2;
    float* big      = wsf + FO_BIG;
    float* out      = (float*)d_out;

    const size_t need_fast = (size_t)FO_BIG * 4 + (size_t)P_TOT * 64 * 4 + 1024;
    const bool fast = ws_size >= need_fast;

    pack_kernel<<<P_TOT / 256, 256, 0, stream>>>(pcd, cloud);
    if (fast) {
        knn_kernel<true><<<NBLK, 512, 0, stream>>>(cloud, W, bias, partials, out, big, nullptr);
        finA_kernel<<<64, 128, 0, stream>>>(partials, part2);
        finB_kernel<<<1, 64, 0, stream>>>(part2, W, bias, gamma, beta, ab, w2);
        final_kernel<<<(P_TOT * 64) / 256, 256, 0, stream>>>(ab, big, out);
    } else {
        knn_kernel<false><<<NBLK, 512, 0, stream>>>(cloud, W, bias, partials, nullptr, nullptr, (int*)big);
        finA_kernel<<<64, 128, 0, stream>>>(partials, part2);
        finB_kernel<<<1, 64, 0, stream>>>(part2, W, bias, gamma, beta, ab, w2);
        out_kernel<<<P_TOT / 4, 256, 0, stream>>>(cloud, (int*)big, w2, out);
    }
}

// Round 7
// 189.998 us; speedup vs baseline: 1.4303x; 1.4303x over previous
//
#include <hip/hip_runtime.h>
#include <math.h>

#define KNN 20
#define NPTS 4096
#define BATCH 8
#define P_TOT (BATCH * NPTS)       // 32768
#define QPW 8                      // queries per wave
#define WPB 8                      // waves per block (512 threads)
#define QPB (QPW * WPB)            // 64 queries per block
#define NBLK (P_TOT / QPB)         // 512 blocks
#define BPB (NPTS / QPB)           // 64 blocks per batch
#define BN_EPS 1e-5
#define NEG_SLOPE 0.2f

// float-offsets into ws
#define FO_CLOUD 0                 // 32768 float4 = 131072 floats
#define FO_PART  131072            // 512 x 128 block partials
#define FO_PART2 196608            // 64 x 128 stage-2 partials
#define FO_AB    655360            // 128 floats (a, shift)
#define FO_W2    655488            // 448 floats (folded W + bias)
#define FO_BIG   655936            // rawmin (2097152 f) or idx (655360 i)

// ---------- kernel 1: pack cloud as float4 (x,y,z,|p|^2) ----------
__global__ __launch_bounds__(256) void pack_kernel(const float* __restrict__ pcd,
                                                   float4* __restrict__ cloud) {
    int i = blockIdx.x * 256 + threadIdx.x;
    float x = pcd[3 * i], y = pcd[3 * i + 1], z = pcd[3 * i + 2];
    float sq = __fadd_rn(__fadd_rn(__fmul_rn(x, x), __fmul_rn(y, y)), __fmul_rn(z, z));
    cloud[i] = make_float4(x, y, z, sq);
}

// distance, bit-exact vs reference (validated R1-R5)
__device__ __forceinline__ float distf(float4 C, float qx, float qy, float qz, float qs) {
    float dot_ = __fadd_rn(__fadd_rn(__fmul_rn(qx, C.x), __fmul_rn(qy, C.y)),
                           __fmul_rn(qz, C.z));
    return fmaf(-2.0f, dot_, __fadd_rn(qs, C.w));
}

// top-2 maintenance, R4's exact select-based version (validated).
// strict <, first-seen kept -> lowest slot on ties (j ascending).
__device__ __forceinline__ void upd2(float& v1, float& v2, int& s1, int& s2, float dd, int j) {
    const bool c1 = dd < v1;
    const bool c2 = dd < v2;
    v2 = c1 ? v1 : (c2 ? dd : v2);
    s2 = c1 ? s1 : (c2 ? j : s2);
    v1 = c1 ? dd : v1;
    s1 = c1 ? j : s1;
}

// half-wave (32-lane) min chains via BitMode ds_swizzle (validated in R5).
// BitMode swizzles lane[4:0] only -> operates independently within each 32-lane half.
__device__ __forceinline__ float hmin_f(float v) {
    v = fminf(v, __int_as_float(__builtin_amdgcn_ds_swizzle(__float_as_int(v), 0x041F)));
    v = fminf(v, __int_as_float(__builtin_amdgcn_ds_swizzle(__float_as_int(v), 0x081F)));
    v = fminf(v, __int_as_float(__builtin_amdgcn_ds_swizzle(__float_as_int(v), 0x101F)));
    v = fminf(v, __int_as_float(__builtin_amdgcn_ds_swizzle(__float_as_int(v), 0x201F)));
    v = fminf(v, __int_as_float(__builtin_amdgcn_ds_swizzle(__float_as_int(v), 0x401F)));
    return v;
}
__device__ __forceinline__ int hmin_i(int v) {
    v = min(v, __builtin_amdgcn_ds_swizzle(v, 0x041F));
    v = min(v, __builtin_amdgcn_ds_swizzle(v, 0x081F));
    v = min(v, __builtin_amdgcn_ds_swizzle(v, 0x101F));
    v = min(v, __builtin_amdgcn_ds_swizzle(v, 0x201F));
    v = min(v, __builtin_amdgcn_ds_swizzle(v, 0x401F));
    return v;
}

// promote group G's second to first, or mask-based recompute of top-2 from LDS.
// 8 groups x 16 slots per lane; slots 0-63 tracked in mk0, 64-127 in mk1.
// All mask bit positions are compile-time constants.
template <int G>
__device__ __forceinline__ void prom(float (&gv1)[8], float (&gv2)[8],
                                     int (&gs1)[8], int (&gs2)[8],
                                     unsigned long long mk0, unsigned long long mk1,
                                     const float4* cl, int sub,
                                     float qx, float qy, float qz, float qs) {
    if (gv2[G] < INFINITY) {
        gv1[G] = gv2[G]; gs1[G] = gs2[G]; gv2[G] = INFINITY;
    } else {
        const unsigned long long mw = (G < 4) ? mk0 : mk1;   // compile-time select
        float w1 = INFINITY, w2 = INFINITY; int t1 = 0, t2 = 0;
#pragma unroll
        for (int e = 0; e < 16; ++e) {
            const int j = G * 16 + e;                        // compile-time slot
            const float4 C = cl[j * 32 + sub];
            float dd = distf(C, qx, qy, qz, qs);
            if ((mw >> ((G & 3) * 16 + e)) & 1ull) dd = INFINITY;  // static bit
            upd2(w1, w2, t1, t2, dd, j);
        }
        gv1[G] = w1; gv2[G] = w2; gs1[G] = t1; gs2[G] = t2;
    }
}

// repair one half's owner lane; win_s is a scalar (readlane result)
__device__ __forceinline__ void repair_half(int win_s, bool own,
                                            float (&gv1)[8], float (&gv2)[8],
                                            int (&gs1)[8], int (&gs2)[8],
                                            unsigned long long& mk0, unsigned long long& mk1,
                                            const float4* cl, int sub,
                                            float qx, float qy, float qz, float qs) {
    const int slot_s = win_s >> 5;                           // scalar, [0,128)
    const unsigned long long b = 1ull << (slot_s & 63);      // scalar shift
    const unsigned long long blo = (slot_s < 64) ? b : 0ull;
    const unsigned long long bhi = (slot_s < 64) ? 0ull : b;
    if (own) { mk0 |= blo; mk1 |= bhi; }                     // record BEFORE prom (R4 order)
    switch (slot_s >> 4) {                                   // scalar branches, 8 cases
        case 0: if (own) prom<0>(gv1, gv2, gs1, gs2, mk0, mk1, cl, sub, qx, qy, qz, qs); break;
        case 1: if (own) prom<1>(gv1, gv2, gs1, gs2, mk0, mk1, cl, sub, qx, qy, qz, qs); break;
        case 2: if (own) prom<2>(gv1, gv2, gs1, gs2, mk0, mk1, cl, sub, qx, qy, qz, qs); break;
        case 3: if (own) prom<3>(gv1, gv2, gs1, gs2, mk0, mk1, cl, sub, qx, qy, qz, qs); break;
        case 4: if (own) prom<4>(gv1, gv2, gs1, gs2, mk0, mk1, cl, sub, qx, qy, qz, qs); break;
        case 5: if (own) prom<5>(gv1, gv2, gs1, gs2, mk0, mk1, cl, sub, qx, qy, qz, qs); break;
        case 6: if (own) prom<6>(gv1, gv2, gs1, gs2, mk0, mk1, cl, sub, qx, qy, qz, qs); break;
        default: if (own) prom<7>(gv1, gv2, gs1, gs2, mk0, mk1, cl, sub, qx, qy, qz, qs); break;
    }
}

// ---------- kernel 2: fused kNN, half-wave split, R4-validated internals ----------
template <bool FAST>
__global__ __attribute__((amdgpu_flat_work_group_size(512, 512), amdgpu_waves_per_eu(4)))
void knn_kernel(const float4* __restrict__ cloud,
                const float* __restrict__ W,
                const float* __restrict__ bias,
                float* __restrict__ partials,
                float* __restrict__ rawmax,
                float* __restrict__ rawmin,
                int* __restrict__ idxo) {
    __shared__ float4 cl[NPTS];    // 64 KB
    const int t = threadIdx.x;
    const int wave = t >> 6, lane = t & 63;
    const int sub = lane & 31;
    const int half = lane >> 5;
    const int bidx = blockIdx.x;
    const int batch = bidx / BPB;
    const int gbase = batch * NPTS;

#pragma unroll
    for (int it = 0; it < NPTS / 512; ++it)
        cl[it * 512 + t] = cloud[gbase + it * 512 + t];
    __syncthreads();

    // per-lane (=channel) folded MLP: raw = qoff + wd0*Cx + wd1*Cy + wd2*Cz
    const float wc3 = W[192 + lane], wc4 = W[256 + lane], wc5 = W[320 + lane];
    const float wd0 = W[lane] - wc3, wd1 = W[64 + lane] - wc4, wd2 = W[128 + lane] - wc5;
    const float bb = bias[lane];
    float se = 0.f, sqs = 0.f;

#pragma unroll 1
    for (int r = 0; r < QPW / 2; ++r) {
        const int qA = (bidx % BPB) * QPB + wave * QPW + r * 2;   // in-batch ids
        const int gqA = gbase + qA;
        const float4 QA4 = cl[qA];
        const float4 QB4 = cl[qA + 1];
        // my half's query coords
        const float qx = half ? QB4.x : QA4.x;
        const float qy = half ? QB4.y : QA4.y;
        const float qz = half ? QB4.z : QA4.z;
        const float qs = half ? QB4.w : QA4.w;
        // channel-phase offsets for BOTH queries (lane = channel)
        const float qoffA = fmaf(wc3, QA4.x, fmaf(wc4, QA4.y, fmaf(wc5, QA4.z, bb)));
        const float qoffB = fmaf(wc3, QB4.x, fmaf(wc4, QB4.y, fmaf(wc5, QB4.z, bb)));

        // ---- distance pass: 128 candidates per lane, 8 groups x 16, top-2/group ----
        float gv1[8], gv2[8];
        int gs1[8], gs2[8];
#pragma unroll
        for (int g = 0; g < 8; ++g) { gv1[g] = INFINITY; gv2[g] = INFINITY; gs1[g] = 0; gs2[g] = 0; }
#pragma unroll
        for (int g = 0; g < 8; ++g) {
#pragma unroll
            for (int h2 = 0; h2 < 2; ++h2) {
#pragma unroll
                for (int e = 0; e < 8; ++e) {
                    const int j = g * 16 + h2 * 8 + e;       // compile-time slot, ascending
                    const float4 C = cl[j * 32 + sub];       // halves share addr: broadcast
                    const float dd = distf(C, qx, qy, qz, qs);
                    upd2(gv1[g], gv2[g], gs1[g], gs2[g], dd, j);
                }
                __builtin_amdgcn_sched_barrier(0);           // cap live loads at 8
            }
        }
        // initial per-lane tournament (ties -> lowest g -> lowest index)
        float dmin = gv1[0]; int bsj = gs1[0];
#pragma unroll
        for (int g = 1; g < 8; ++g) if (gv1[g] < dmin) { dmin = gv1[g]; bsj = gs1[g]; }
        int mmin = (bsj << 5) | sub;

        unsigned long long mk0 = 0ull, mk1 = 0ull;
        float hmaxA = -INFINITY, hminA = INFINITY;
        float hmaxB = -INFINITY, hminB = INFINITY;

#pragma unroll 1
        for (int p = 0; p < KNN; ++p) {
            // per-half min by (distance, index) -- branchless, ties -> lowest index
            const float gmin = hmin_f(dmin);
            const int cand = (dmin == gmin) ? mmin : 0x7FFFFFFF;
            const int win = hmin_i(cand);                    // uniform within each half

            if (!FAST) { if (sub == 0) idxo[(gbase + qA + half) * KNN + p] = win; }

            // scalar winners for the wave-wide channel phase
            const int winA_s = __builtin_amdgcn_readlane(win, 0);
            const int winB_s = __builtin_amdgcn_readlane(win, 32);
            const float4 CA = cl[winA_s];
            const float4 CB = cl[winB_s];
            const float rawA = fmaf(wd0, CA.x, fmaf(wd1, CA.y, fmaf(wd2, CA.z, qoffA)));
            const float rawB = fmaf(wd0, CB.x, fmaf(wd1, CB.y, fmaf(wd2, CB.z, qoffB)));
            se += rawA; sqs = fmaf(rawA, rawA, sqs);
            hmaxA = fmaxf(hmaxA, rawA); hminA = fminf(hminA, rawA);
            se += rawB; sqs = fmaf(rawB, rawB, sqs);
            hmaxB = fmaxf(hmaxB, rawB); hminB = fminf(hminB, rawB);

            if (p < KNN - 1) {
                const bool ownA = (half == 0) && ((winA_s & 31) == sub);
                const bool ownB = (half == 1) && ((winB_s & 31) == sub);
                repair_half(winA_s, ownA, gv1, gv2, gs1, gs2, mk0, mk1, cl, sub, qx, qy, qz, qs);
                repair_half(winB_s, ownB, gv1, gv2, gs1, gs2, mk0, mk1, cl, sub, qx, qy, qz, qs);
                // rebuild per-lane tournament (idempotent for non-owners)
                float nv = gv1[0]; int ns = gs1[0];
#pragma unroll
                for (int g = 1; g < 8; ++g) if (gv1[g] < nv) { nv = gv1[g]; ns = gs1[g]; }
                dmin = nv; mmin = (ns << 5) | sub;
            }
        }

        if (FAST) {
            rawmax[gqA * 64 + lane] = hmaxA;
            rawmin[gqA * 64 + lane] = hminA;
            rawmax[(gqA + 1) * 64 + lane] = hmaxB;
            rawmin[(gqA + 1) * 64 + lane] = hminB;
        }
    }

    // ---- cross-wave stats reduce (reuse cl LDS) ----
    __syncthreads();
    float* sred = (float*)cl;
    sred[wave * 128 + lane] = se;
    sred[wave * 128 + 64 + lane] = sqs;
    __syncthreads();
    if (t < 128) {
        float s = 0.f;
#pragma unroll
        for (int w = 0; w < WPB; ++w) s += sred[w * 128 + t];
        partials[bidx * 128 + t] = s;
    }
}

// ---------- kernel 3a: reduce 512 block-partials -> 64 ----------
__global__ __launch_bounds__(128) void finA_kernel(const float* __restrict__ partials,
                                                   float* __restrict__ part2) {
    const int b = blockIdx.x, t = threadIdx.x;   // 64 blocks x 128 threads
    float s = 0.f;
#pragma unroll
    for (int i = 0; i < 8; ++i) s += partials[(b * 8 + i) * 128 + t];
    part2[b * 128 + t] = s;
}

// ---------- kernel 3b: finalize BN, fold affine ----------
__global__ __launch_bounds__(64) void finB_kernel(const float* __restrict__ part2,
                                                  const float* __restrict__ W,
                                                  const float* __restrict__ bias,
                                                  const float* __restrict__ gamma,
                                                  const float* __restrict__ beta,
                                                  float* __restrict__ ab,
                                                  float* __restrict__ w2) {
    const int c = threadIdx.x;   // 64 threads
    double s0 = 0.0, s1 = 0.0, q0 = 0.0, q1 = 0.0;
    for (int i = 0; i < 64; i += 2) {
        s0 += (double)part2[i * 128 + c];
        q0 += (double)part2[i * 128 + 64 + c];
        s1 += (double)part2[(i + 1) * 128 + c];
        q1 += (double)part2[(i + 1) * 128 + 64 + c];
    }
    const double cnt = (double)P_TOT * KNN;
    double mean = (s0 + s1) / cnt;
    double var = (q0 + q1) / cnt - mean * mean;
    double a = (double)gamma[c] / sqrt(var + BN_EPS);
    float af = (float)a;
    float sh = (float)((double)beta[c] - mean * a);
    ab[c] = af;
    ab[64 + c] = sh;
#pragma unroll
    for (int f = 0; f < 6; ++f) w2[f * 64 + c] = W[f * 64 + c] * af;
    w2[384 + c] = fmaf(bias[c], af, sh);
}

// ---------- kernel 4a (fast): elementwise BN+LeakyReLU on raw max/min ----------
__global__ __launch_bounds__(256) void final_kernel(const float* __restrict__ ab,
                                                    const float* __restrict__ rawmin,
                                                    float* __restrict__ out) {
    int i = blockIdx.x * 256 + threadIdx.x;
    int c = i & 63;
    float a = ab[c], sh = ab[64 + c];
    float va = fmaf(a, out[i], sh);       // out currently holds rawmax
    float vb = fmaf(a, rawmin[i], sh);
    va = va >= 0.f ? va : NEG_SLOPE * va;
    vb = vb >= 0.f ? vb : NEG_SLOPE * vb;
    out[i] = fmaxf(va, vb);               // monotone: covers a>=0 and a<0
}

// ---------- kernel 4b (fallback): gather + folded MLP + maxpool ----------
__global__ __launch_bounds__(256) void out_kernel(const float4* __restrict__ cloud,
                                                  const int* __restrict__ idxo,
                                                  const float* __restrict__ w2,
                                                  float* __restrict__ out) {
    const int t = threadIdx.x, c = t & 63;
    const int gp = blockIdx.x * 4 + (t >> 6);
    const int gb = gp & ~(NPTS - 1);
    const float wc0 = w2[c], wc1 = w2[64 + c], wc2 = w2[128 + c];
    const float wc3 = w2[192 + c], wc4 = w2[256 + c], wc5 = w2[320 + c];
    const float bc = w2[384 + c];
    const float4 Q = cloud[gp];
    float vmax = -INFINITY;
    for (int k = 0; k < KNN; ++k) {
        const int m = idxo[gp * KNN + k];
        const float4 C = cloud[gb + m];
        float h = bc;
        h = fmaf(wc0, C.x, h);
        h = fmaf(wc1, C.y, h);
        h = fmaf(wc2, C.z, h);
        h = fmaf(wc3, Q.x - C.x, h);
        h = fmaf(wc4, Q.y - C.y, h);
        h = fmaf(wc5, Q.z - C.z, h);
        h = h >= 0.f ? h : NEG_SLOPE * h;
        vmax = fmaxf(vmax, h);
    }
    out[gp * 64 + c] = vmax;
}

extern "C" void kernel_launch(void* const* d_in, const int* in_sizes, int n_in,
                              void* d_out, int out_size, void* d_ws, size_t ws_size,
                              hipStream_t stream) {
    const float* pcd   = (const float*)d_in[0];
    const float* W     = (const float*)d_in[1];
    const float* bias  = (const float*)d_in[2];
    const float* gamma = (const float*)d_in[3];
    const float* beta  = (const float*)d_in[4];

    float* wsf = (float*)d_ws;
    float4* cloud   = (float4*)(wsf + FO_CLOUD);
    float* partials = wsf + FO_PART;
    float* part2    = wsf + FO_PART2;
    float* ab       = wsf + FO_AB;
    float* w2       = wsf + FO_W2;
    float* big      = wsf + FO_BIG;
    float* out      = (float*)d_out;

    const size_t need_fast = (size_t)FO_BIG * 4 + (size_t)P_TOT * 64 * 4 + 1024;
    const bool fast = ws_size >= need_fast;

    pack_kernel<<<P_TOT / 256, 256, 0, stream>>>(pcd, cloud);
    if (fast) {
        knn_kernel<true><<<NBLK, 512, 0, stream>>>(cloud, W, bias, partials, out, big, nullptr);
        finA_kernel<<<64, 128, 0, stream>>>(partials, part2);
        finB_kernel<<<1, 64, 0, stream>>>(part2, W, bias, gamma, beta, ab, w2);
        final_kernel<<<(P_TOT * 64) / 256, 256, 0, stream>>>(ab, big, out);
    } else {
        knn_kernel<false><<<NBLK, 512, 0, stream>>>(cloud, W, bias, partials, nullptr, nullptr, (int*)big);
        finA_kernel<<<64, 128, 0, stream>>>(partials, part2);
        finB_kernel<<<1, 64, 0, stream>>>(part2, W, bias, gamma, beta, ab, w2);
        out_kernel<<<P_TOT / 4, 256, 0, stream>>>(cloud, (int*)big, w2, out);
    }
}

// Round 9
// 186.439 us; speedup vs baseline: 1.4576x; 1.0191x over previous
//
#include <hip/hip_runtime.h>
#include <math.h>

#define KNN 20
#define NPTS 4096
#define BATCH 8
#define P_TOT (BATCH * NPTS)       // 32768
#define QPW 8                      // queries per wave
#define WPB 8                      // waves per block (512 threads)
#define QPB (QPW * WPB)            // 64 queries per block
#define NBLK (P_TOT / QPB)         // 512 blocks
#define BPB (NPTS / QPB)           // 64 blocks per batch
#define BN_EPS 1e-5
#define NEG_SLOPE 0.2f

// float-offsets into ws
#define FO_CLOUD 0                 // 32768 float4 = 131072 floats
#define FO_PART  131072            // 512 x 128 block partials
#define FO_PART2 196608            // 64 x 128 stage-2 partials
#define FO_AB    655360            // 128 floats (a, shift)
#define FO_W2    655488            // 448 floats (folded W + bias)
#define FO_BIG   655936            // rawmin (2097152 f) or idx (655360 i)

// ---------- kernel 1: pack cloud as float4 (x,y,z,|p|^2) ----------
__global__ __launch_bounds__(256) void pack_kernel(const float* __restrict__ pcd,
                                                   float4* __restrict__ cloud) {
    int i = blockIdx.x * 256 + threadIdx.x;
    float x = pcd[3 * i], y = pcd[3 * i + 1], z = pcd[3 * i + 2];
    float sq = __fadd_rn(__fadd_rn(__fmul_rn(x, x), __fmul_rn(y, y)), __fmul_rn(z, z));
    cloud[i] = make_float4(x, y, z, sq);
}

// distance, bit-exact vs reference (validated R1-R7)
__device__ __forceinline__ float distf(float4 C, float qx, float qy, float qz, float qs) {
    float dot_ = __fadd_rn(__fadd_rn(__fmul_rn(qx, C.x), __fmul_rn(qy, C.y)),
                           __fmul_rn(qz, C.z));
    return fmaf(-2.0f, dot_, __fadd_rn(qs, C.w));
}

// top-2 maintenance, R4's exact select-based version (validated).
// strict <, first-seen kept -> lowest slot on ties (j ascending).
__device__ __forceinline__ void upd2(float& v1, float& v2, int& s1, int& s2, float dd, int j) {
    const bool c1 = dd < v1;
    const bool c2 = dd < v2;
    v2 = c1 ? v1 : (c2 ? dd : v2);
    s2 = c1 ? s1 : (c2 ? j : s2);
    v1 = c1 ? dd : v1;
    s1 = c1 ? j : s1;
}

// ---- half-wave (32-lane) min chains via DPP (steps 1-4) + one swizzle (xor16) ----
// DPP ctrl: 0xB1 = quad_perm[1,0,3,2] (xor1), 0x4E = quad_perm[2,3,0,1] (xor2),
// 0x141 = row_half_mirror (pairs the two quads within 8; valid after quad-min),
// 0x140 = row_mirror (pairs the two 8-groups within 16). Final xor16 within 32
// via BitMode ds_swizzle 0x401F (validated R5/R7). No op crosses the 32-lane half.
// ctrl must be a compile-time literal -> template parameter.
template <int CTRL>
__device__ __forceinline__ int dpp_mov(int v) {
    return __builtin_amdgcn_update_dpp(v, v, CTRL, 0xf, 0xf, false);
}
__device__ __forceinline__ float hmin_f(float v) {
    v = fminf(v, __int_as_float(dpp_mov<0xB1>(__float_as_int(v))));
    v = fminf(v, __int_as_float(dpp_mov<0x4E>(__float_as_int(v))));
    v = fminf(v, __int_as_float(dpp_mov<0x141>(__float_as_int(v))));
    v = fminf(v, __int_as_float(dpp_mov<0x140>(__float_as_int(v))));
    v = fminf(v, __int_as_float(__builtin_amdgcn_ds_swizzle(__float_as_int(v), 0x401F)));
    return v;
}
__device__ __forceinline__ int hmin_i(int v) {
    v = min(v, dpp_mov<0xB1>(v));
    v = min(v, dpp_mov<0x4E>(v));
    v = min(v, dpp_mov<0x141>(v));
    v = min(v, dpp_mov<0x140>(v));
    v = min(v, __builtin_amdgcn_ds_swizzle(v, 0x401F));
    return v;
}

// promote group G's second to first, or mask-based recompute of top-2 from LDS.
// 8 groups x 16 slots per lane; slots 0-63 tracked in mk0, 64-127 in mk1.
// All mask bit positions are compile-time constants.
template <int G>
__device__ __forceinline__ void prom(float (&gv1)[8], float (&gv2)[8],
                                     int (&gs1)[8], int (&gs2)[8],
                                     unsigned long long mk0, unsigned long long mk1,
                                     const float4* cl, int sub,
                                     float qx, float qy, float qz, float qs) {
    if (gv2[G] < INFINITY) {
        gv1[G] = gv2[G]; gs1[G] = gs2[G]; gv2[G] = INFINITY;
    } else {
        const unsigned long long mw = (G < 4) ? mk0 : mk1;   // compile-time select
        float w1 = INFINITY, w2 = INFINITY; int t1 = 0, t2 = 0;
#pragma unroll
        for (int e = 0; e < 16; ++e) {
            const int j = G * 16 + e;                        // compile-time slot
            const float4 C = cl[j * 32 + sub];
            float dd = distf(C, qx, qy, qz, qs);
            if ((mw >> ((G & 3) * 16 + e)) & 1ull) dd = INFINITY;  // static bit
            upd2(w1, w2, t1, t2, dd, j);
        }
        gv1[G] = w1; gv2[G] = w2; gs1[G] = t1; gs2[G] = t2;
    }
}

// repair one half's owner lane; win_s is a scalar (readlane result)
__device__ __forceinline__ void repair_half(int win_s, bool own,
                                            float (&gv1)[8], float (&gv2)[8],
                                            int (&gs1)[8], int (&gs2)[8],
                                            unsigned long long& mk0, unsigned long long& mk1,
                                            const float4* cl, int sub,
                                            float qx, float qy, float qz, float qs) {
    const int slot_s = win_s >> 5;                           // scalar, [0,128)
    const unsigned long long b = 1ull << (slot_s & 63);      // scalar shift
    const unsigned long long blo = (slot_s < 64) ? b : 0ull;
    const unsigned long long bhi = (slot_s < 64) ? 0ull : b;
    if (own) { mk0 |= blo; mk1 |= bhi; }                     // record BEFORE prom (R4 order)
    switch (slot_s >> 4) {                                   // scalar branches, 8 cases
        case 0: if (own) prom<0>(gv1, gv2, gs1, gs2, mk0, mk1, cl, sub, qx, qy, qz, qs); break;
        case 1: if (own) prom<1>(gv1, gv2, gs1, gs2, mk0, mk1, cl, sub, qx, qy, qz, qs); break;
        case 2: if (own) prom<2>(gv1, gv2, gs1, gs2, mk0, mk1, cl, sub, qx, qy, qz, qs); break;
        case 3: if (own) prom<3>(gv1, gv2, gs1, gs2, mk0, mk1, cl, sub, qx, qy, qz, qs); break;
        case 4: if (own) prom<4>(gv1, gv2, gs1, gs2, mk0, mk1, cl, sub, qx, qy, qz, qs); break;
        case 5: if (own) prom<5>(gv1, gv2, gs1, gs2, mk0, mk1, cl, sub, qx, qy, qz, qs); break;
        case 6: if (own) prom<6>(gv1, gv2, gs1, gs2, mk0, mk1, cl, sub, qx, qy, qz, qs); break;
        default: if (own) prom<7>(gv1, gv2, gs1, gs2, mk0, mk1, cl, sub, qx, qy, qz, qs); break;
    }
}

// ---------- kernel 2: fused kNN, half-wave split, R7-validated structure ----------
template <bool FAST>
__global__ __attribute__((amdgpu_flat_work_group_size(512, 512), amdgpu_waves_per_eu(4)))
void knn_kernel(const float4* __restrict__ cloud,
                const float* __restrict__ W,
                const float* __restrict__ bias,
                float* __restrict__ partials,
                float* __restrict__ rawmax,
                float* __restrict__ rawmin,
                int* __restrict__ idxo) {
    __shared__ float4 cl[NPTS];    // 64 KB
    const int t = threadIdx.x;
    const int wave = t >> 6, lane = t & 63;
    const int sub = lane & 31;
    const int half = lane >> 5;
    const int bidx = blockIdx.x;
    const int batch = bidx / BPB;
    const int gbase = batch * NPTS;

#pragma unroll
    for (int it = 0; it < NPTS / 512; ++it)
        cl[it * 512 + t] = cloud[gbase + it * 512 + t];
    __syncthreads();

    // per-lane (=channel) folded MLP: raw = qoff + wd0*Cx + wd1*Cy + wd2*Cz
    const float wc3 = W[192 + lane], wc4 = W[256 + lane], wc5 = W[320 + lane];
    const float wd0 = W[lane] - wc3, wd1 = W[64 + lane] - wc4, wd2 = W[128 + lane] - wc5;
    const float bb = bias[lane];
    float se = 0.f, sqs = 0.f;

#pragma unroll 1
    for (int r = 0; r < QPW / 2; ++r) {
        const int qA = (bidx % BPB) * QPB + wave * QPW + r * 2;   // in-batch ids
        const int gqA = gbase + qA;
        const float4 QA4 = cl[qA];
        const float4 QB4 = cl[qA + 1];
        // my half's query coords
        const float qx = half ? QB4.x : QA4.x;
        const float qy = half ? QB4.y : QA4.y;
        const float qz = half ? QB4.z : QA4.z;
        const float qs = half ? QB4.w : QA4.w;
        // channel-phase offsets for BOTH queries (lane = channel)
        const float qoffA = fmaf(wc3, QA4.x, fmaf(wc4, QA4.y, fmaf(wc5, QA4.z, bb)));
        const float qoffB = fmaf(wc3, QB4.x, fmaf(wc4, QB4.y, fmaf(wc5, QB4.z, bb)));

        // ---- distance pass: 128 candidates per lane, 8 groups x 16, top-2/group ----
        float gv1[8], gv2[8];
        int gs1[8], gs2[8];
#pragma unroll
        for (int g = 0; g < 8; ++g) { gv1[g] = INFINITY; gv2[g] = INFINITY; gs1[g] = 0; gs2[g] = 0; }
#pragma unroll
        for (int g = 0; g < 8; ++g) {
#pragma unroll
            for (int h2 = 0; h2 < 2; ++h2) {
#pragma unroll
                for (int e = 0; e < 8; ++e) {
                    const int j = g * 16 + h2 * 8 + e;       // compile-time slot, ascending
                    const float4 C = cl[j * 32 + sub];       // halves share addr: broadcast
                    const float dd = distf(C, qx, qy, qz, qs);
                    upd2(gv1[g], gv2[g], gs1[g], gs2[g], dd, j);
                }
                __builtin_amdgcn_sched_barrier(0);           // cap live loads at 8
            }
        }
        // initial per-lane tournament (ties -> lowest g -> lowest index)
        float dmin = gv1[0]; int bsj = gs1[0];
#pragma unroll
        for (int g = 1; g < 8; ++g) if (gv1[g] < dmin) { dmin = gv1[g]; bsj = gs1[g]; }
        int mmin = (bsj << 5) | sub;

        unsigned long long mk0 = 0ull, mk1 = 0ull;
        float hmaxA = -INFINITY, hminA = INFINITY;
        float hmaxB = -INFINITY, hminB = INFINITY;

#pragma unroll 1
        for (int p = 0; p < KNN; ++p) {
            // per-half min by (distance, index) -- branchless, ties -> lowest index
            const float gmin = hmin_f(dmin);
            const int cand = (dmin == gmin) ? mmin : 0x7FFFFFFF;
            const int win = hmin_i(cand);                    // uniform within each half

            if (!FAST) { if (sub == 0) idxo[(gbase + qA + half) * KNN + p] = win; }

            // scalar winners for the wave-wide channel phase
            const int winA_s = __builtin_amdgcn_readlane(win, 0);
            const int winB_s = __builtin_amdgcn_readlane(win, 32);
            const float4 CA = cl[winA_s];
            const float4 CB = cl[winB_s];
            const float rawA = fmaf(wd0, CA.x, fmaf(wd1, CA.y, fmaf(wd2, CA.z, qoffA)));
            const float rawB = fmaf(wd0, CB.x, fmaf(wd1, CB.y, fmaf(wd2, CB.z, qoffB)));
            se += rawA; sqs = fmaf(rawA, rawA, sqs);
            hmaxA = fmaxf(hmaxA, rawA); hminA = fminf(hminA, rawA);
            se += rawB; sqs = fmaf(rawB, rawB, sqs);
            hmaxB = fmaxf(hmaxB, rawB); hminB = fminf(hminB, rawB);

            if (p < KNN - 1) {
                const bool ownA = (half == 0) && ((winA_s & 31) == sub);
                const bool ownB = (half == 1) && ((winB_s & 31) == sub);
                repair_half(winA_s, ownA, gv1, gv2, gs1, gs2, mk0, mk1, cl, sub, qx, qy, qz, qs);
                repair_half(winB_s, ownB, gv1, gv2, gs1, gs2, mk0, mk1, cl, sub, qx, qy, qz, qs);
                // rebuild per-lane tournament (idempotent for non-owners)
                float nv = gv1[0]; int ns = gs1[0];
#pragma unroll
                for (int g = 1; g < 8; ++g) if (gv1[g] < nv) { nv = gv1[g]; ns = gs1[g]; }
                dmin = nv; mmin = (ns << 5) | sub;
            }
        }

        if (FAST) {
            rawmax[gqA * 64 + lane] = hmaxA;
            rawmin[gqA * 64 + lane] = hminA;
            rawmax[(gqA + 1) * 64 + lane] = hmaxB;
            rawmin[(gqA + 1) * 64 + lane] = hminB;
        }
    }

    // ---- cross-wave stats reduce (reuse cl LDS) ----
    __syncthreads();
    float* sred = (float*)cl;
    sred[wave * 128 + lane] = se;
    sred[wave * 128 + 64 + lane] = sqs;
    __syncthreads();
    if (t < 128) {
        float s = 0.f;
#pragma unroll
        for (int w = 0; w < WPB; ++w) s += sred[w * 128 + t];
        partials[bidx * 128 + t] = s;
    }
}

// ---------- kernel 3a: reduce 512 block-partials -> 64 ----------
__global__ __launch_bounds__(128) void finA_kernel(const float* __restrict__ partials,
                                                   float* __restrict__ part2) {
    const int b = blockIdx.x, t = threadIdx.x;   // 64 blocks x 128 threads
    float s = 0.f;
#pragma unroll
    for (int i = 0; i < 8; ++i) s += partials[(b * 8 + i) * 128 + t];
    part2[b * 128 + t] = s;
}

// ---------- kernel 3b: finalize BN, fold affine ----------
__global__ __launch_bounds__(64) void finB_kernel(const float* __restrict__ part2,
                                                  const float* __restrict__ W,
                                                  const float* __restrict__ bias,
                                                  const float* __restrict__ gamma,
                                                  const float* __restrict__ beta,
                                                  float* __restrict__ ab,
                                                  float* __restrict__ w2) {
    const int c = threadIdx.x;   // 64 threads
    double s0 = 0.0, s1 = 0.0, q0 = 0.0, q1 = 0.0;
    for (int i = 0; i < 64; i += 2) {
        s0 += (double)part2[i * 128 + c];
        q0 += (double)part2[i * 128 + 64 + c];
        s1 += (double)part2[(i + 1) * 128 + c];
        q1 += (double)part2[(i + 1) * 128 + 64 + c];
    }
    const double cnt = (double)P_TOT * KNN;
    double mean = (s0 + s1) / cnt;
    double var = (q0 + q1) / cnt - mean * mean;
    double a = (double)gamma[c] / sqrt(var + BN_EPS);
    float af = (float)a;
    float sh = (float)((double)beta[c] - mean * a);
    ab[c] = af;
    ab[64 + c] = sh;
#pragma unroll
    for (int f = 0; f < 6; ++f) w2[f * 64 + c] = W[f * 64 + c] * af;
    w2[384 + c] = fmaf(bias[c], af, sh);
}

// ---------- kernel 4a (fast): elementwise BN+LeakyReLU on raw max/min ----------
__global__ __launch_bounds__(256) void final_kernel(const float* __restrict__ ab,
                                                    const float* __restrict__ rawmin,
                                                    float* __restrict__ out) {
    int i = blockIdx.x * 256 + threadIdx.x;
    int c = i & 63;
    float a = ab[c], sh = ab[64 + c];
    float va = fmaf(a, out[i], sh);       // out currently holds rawmax
    float vb = fmaf(a, rawmin[i], sh);
    va = va >= 0.f ? va : NEG_SLOPE * va;
    vb = vb >= 0.f ? vb : NEG_SLOPE * vb;
    out[i] = fmaxf(va, vb);               // monotone: covers a>=0 and a<0
}

// ---------- kernel 4b (fallback): gather + folded MLP + maxpool ----------
__global__ __launch_bounds__(256) void out_kernel(const float4* __restrict__ cloud,
                                                  const int* __restrict__ idxo,
                                                  const float* __restrict__ w2,
                                                  float* __restrict__ out) {
    const int t = threadIdx.x, c = t & 63;
    const int gp = blockIdx.x * 4 + (t >> 6);
    const int gb = gp & ~(NPTS - 1);
    const float wc0 = w2[c], wc1 = w2[64 + c], wc2 = w2[128 + c];
    const float wc3 = w2[192 + c], wc4 = w2[256 + c], wc5 = w2[320 + c];
    const float bc = w2[384 + c];
    const float4 Q = cloud[gp];
    float vmax = -INFINITY;
    for (int k = 0; k < KNN; ++k) {
        const int m = idxo[gp * KNN + k];
        const float4 C = cloud[gb + m];
        float h = bc;
        h = fmaf(wc0, C.x, h);
        h = fmaf(wc1, C.y, h);
        h = fmaf(wc2, C.z, h);
        h = fmaf(wc3, Q.x - C.x, h);
        h = fmaf(wc4, Q.y - C.y, h);
        h = fmaf(wc5, Q.z - C.z, h);
        h = h >= 0.f ? h : NEG_SLOPE * h;
        vmax = fmaxf(vmax, h);
    }
    out[gp * 64 + c] = vmax;
}

extern "C" void kernel_launch(void* const* d_in, const int* in_sizes, int n_in,
                              void* d_out, int out_size, void* d_ws, size_t ws_size,
                              hipStream_t stream) {
    const float* pcd   = (const float*)d_in[0];
    const float* W     = (const float*)d_in[1];
    const float* bias  = (const float*)d_in[2];
    const float* gamma = (const float*)d_in[3];
    const float* beta  = (const float*)d_in[4];

    float* wsf = (float*)d_ws;
    float4* cloud   = (float4*)(wsf + FO_CLOUD);
    float* partials = wsf + FO_PART;
    float* part2    = wsf + FO_PART2;
    float* ab       = wsf + FO_AB;
    float* w2       = wsf + FO_W2;
    float* big      = wsf + FO_BIG;
    float* out      = (float*)d_out;

    const size_t need_fast = (size_t)FO_BIG * 4 + (size_t)P_TOT * 64 * 4 + 1024;
    const bool fast = ws_size >= need_fast;

    pack_kernel<<<P_TOT / 256, 256, 0, stream>>>(pcd, cloud);
    if (fast) {
        knn_kernel<true><<<NBLK, 512, 0, stream>>>(cloud, W, bias, partials, out, big, nullptr);
        finA_kernel<<<64, 128, 0, stream>>>(partials, part2);
        finB_kernel<<<1, 64, 0, stream>>>(part2, W, bias, gamma, beta, ab, w2);
        final_kernel<<<(P_TOT * 64) / 256, 256, 0, stream>>>(ab, big, out);
    } else {
        knn_kernel<false><<<NBLK, 512, 0, stream>>>(cloud, W, bias, partials, nullptr, nullptr, (int*)big);
        finA_kernel<<<64, 128, 0, stream>>>(partials, part2);
        finB_kernel<<<1, 64, 0, stream>>>(part2, W, bias, gamma, beta, ab, w2);
        out_kernel<<<P_TOT / 4, 256, 0, stream>>>(cloud, (int*)big, w2, out);
    }
}